// Round 2
// baseline (97.212 us; speedup 1.0000x reference)
//
#include <hip/hip_runtime.h>
#include <hip/hip_cooperative_groups.h>

namespace cg = cooperative_groups;

#define DD 256        // feature dim
#define CC 4096       // number of centers
#define THREADS 256   // 4 waves / block
#define NBLK 256      // cooperative grid: 1 block / CU guaranteed resident
#define NW (NBLK * THREADS / 64)  // 1024 waves
#define RPW (CC / NW)             // 4 rows per wave
#define D4 (DD / 4)               // 64 float4 columns

// ---------------------------------------------------------------------------
// DensityLoss forward, collapsed O(C^2 D) -> O(C D), single cooperative kernel:
//   t[d]  = sum_i centers[i][d];  S = sum_i ||c_i||^2
//   cd[i] = (C*||c_i||^2 + S - 2*c_i.t) / (C-1)      (diagonal term == 0)
//   out   = (sum cd / C) / var(cd, ddof=1) / N
// Phases separated by grid.sync(); every reduction is fixed-order
// (register tree + wave butterfly + LDS tree) -> deterministic, no atomics.
// centers is read exactly once: each wave keeps its 4 rows in registers
// across the grid syncs.
// ---------------------------------------------------------------------------
__global__ __launch_bounds__(THREADS) void fused_density(
    const float* __restrict__ centers,
    float* __restrict__ t_part,    // [NW][DD]
    float* __restrict__ S_part,    // [NW]
    float* __restrict__ t_glob,    // [DD]
    float* __restrict__ S_glob,    // [1]
    double* __restrict__ cd_part,  // [NW]
    double* __restrict__ cd2_part, // [NW]
    float* __restrict__ out, long long N) {
  cg::grid_group grid = cg::this_grid();
  const int tx = threadIdx.x;
  const int wave = (blockIdx.x * THREADS + tx) >> 6;
  const int lane = tx & 63;

  __shared__ float4 redT[THREADS];
  __shared__ float redS[THREADS];
  __shared__ double redC[THREADS];
  __shared__ double redC2[THREADS];

  // ---- phase 1: per-wave column sums + sum-of-squares ----
  const float4* src = (const float4*)centers + (size_t)wave * RPW * D4 + lane;
  float4 v0 = src[0 * D4];
  float4 v1 = src[1 * D4];
  float4 v2 = src[2 * D4];
  float4 v3 = src[3 * D4];
  float4 ta;
  ta.x = (v0.x + v1.x) + (v2.x + v3.x);
  ta.y = (v0.y + v1.y) + (v2.y + v3.y);
  ta.z = (v0.z + v1.z) + (v2.z + v3.z);
  ta.w = (v0.w + v1.w) + (v2.w + v3.w);
  ((float4*)t_part)[wave * D4 + lane] = ta;
  float ss = (v0.x * v0.x + v0.y * v0.y + v0.z * v0.z + v0.w * v0.w) +
             (v1.x * v1.x + v1.y * v1.y + v1.z * v1.z + v1.w * v1.w) +
             (v2.x * v2.x + v2.y * v2.y + v2.z * v2.z + v2.w * v2.w) +
             (v3.x * v3.x + v3.y * v3.y + v3.z * v3.z + v3.w * v3.w);
  #pragma unroll
  for (int off = 32; off; off >>= 1) ss += __shfl_xor(ss, off, 64);
  if (lane == 0) S_part[wave] = ss;

  grid.sync();

  // ---- phase 1b: tree-reduce t_part -> t_glob (64 blocks, 1 f4-col each),
  //                S_part -> S_glob (block 64) ----
  if (blockIdx.x < 64) {
    const int col = blockIdx.x;
    const float4* tp = (const float4*)t_part;
    float4 a = tp[(tx + 0 * 256) * D4 + col];
    float4 b = tp[(tx + 1 * 256) * D4 + col];
    float4 c = tp[(tx + 2 * 256) * D4 + col];
    float4 d = tp[(tx + 3 * 256) * D4 + col];
    float4 s;
    s.x = (a.x + b.x) + (c.x + d.x);
    s.y = (a.y + b.y) + (c.y + d.y);
    s.z = (a.z + b.z) + (c.z + d.z);
    s.w = (a.w + b.w) + (c.w + d.w);
    redT[tx] = s;
    __syncthreads();
    #pragma unroll
    for (int st = 128; st; st >>= 1) {
      if (tx < st) {
        float4 o = redT[tx + st];
        float4 m = redT[tx];
        m.x += o.x; m.y += o.y; m.z += o.z; m.w += o.w;
        redT[tx] = m;
      }
      __syncthreads();
    }
    if (tx == 0) ((float4*)t_glob)[col] = redT[0];
  } else if (blockIdx.x == 64) {
    float a = (S_part[tx] + S_part[tx + 256]) + (S_part[tx + 512] + S_part[tx + 768]);
    redS[tx] = a;
    __syncthreads();
    #pragma unroll
    for (int st = 128; st; st >>= 1) {
      if (tx < st) redS[tx] += redS[tx + st];
      __syncthreads();
    }
    if (tx == 0) S_glob[0] = redS[0];
  }

  grid.sync();

  // ---- phase 2: cd per row (rows still live in v0..v3), double accumulate --
  float4 t4 = ((const float4*)t_glob)[lane];
  const float S = S_glob[0];
  const float Cf = (float)CC;
  const double inv = 1.0 / (double)(CC - 1);
  double cds = 0.0, cd2 = 0.0;
  float4 vr;
  #pragma unroll
  for (int r = 0; r < RPW; ++r) {
    vr = (r == 0) ? v0 : (r == 1) ? v1 : (r == 2) ? v2 : v3;
    float u = (Cf * vr.x - 2.f * t4.x) * vr.x + (Cf * vr.y - 2.f * t4.y) * vr.y +
              (Cf * vr.z - 2.f * t4.z) * vr.z + (Cf * vr.w - 2.f * t4.w) * vr.w;
    #pragma unroll
    for (int off = 32; off; off >>= 1) u += __shfl_xor(u, off, 64);
    if (lane == 0) {
      double cd = ((double)u + (double)S) * inv;
      cds += cd;
      cd2 += cd * cd;
    }
  }
  if (lane == 0) {
    cd_part[wave] = cds;
    cd2_part[wave] = cd2;
  }

  grid.sync();

  // ---- phase 3: block 0 combines NW double partials -> scalar ----
  if (blockIdx.x == 0) {
    double a = (cd_part[tx] + cd_part[tx + 256]) + (cd_part[tx + 512] + cd_part[tx + 768]);
    double b = (cd2_part[tx] + cd2_part[tx + 256]) + (cd2_part[tx + 512] + cd2_part[tx + 768]);
    redC[tx] = a;
    redC2[tx] = b;
    __syncthreads();
    #pragma unroll
    for (int st = 128; st; st >>= 1) {
      if (tx < st) {
        redC[tx] += redC[tx + st];
        redC2[tx] += redC2[tx + st];
      }
      __syncthreads();
    }
    if (tx == 0) {
      double s = redC[0], s2 = redC2[0];
      double mean = s / (double)CC;
      double var = (s2 - s * s / (double)CC) / (double)(CC - 1);
      out[0] = (float)(mean / var / (double)N);
    }
  }
}

extern "C" void kernel_launch(void* const* d_in, const int* in_sizes, int n_in,
                              void* d_out, int out_size, void* d_ws,
                              size_t ws_size, hipStream_t stream) {
  const float* centers = (const float*)d_in[0];
  long long N = (long long)in_sizes[2];  // labels.shape[0]
  (void)n_in; (void)out_size; (void)ws_size;

  // Workspace layout (all offsets 16B-aligned; total ~1.07 MB):
  char* ws = (char*)d_ws;
  float* t_part = (float*)ws;                               // NW*DD*4 = 1 MB
  float* S_part = (float*)(ws + (size_t)NW * DD * 4);       // 4 KB
  float* t_glob = (float*)(ws + (size_t)NW * DD * 4 + NW * 4);  // 1 KB
  float* S_glob = t_glob + DD;                              // 16 B slot
  double* cd_part =
      (double*)(ws + (size_t)NW * DD * 4 + NW * 4 + DD * 4 + 16);  // 8 KB
  double* cd2_part = cd_part + NW;                          // 8 KB
  float* outp = (float*)d_out;

  void* args[] = {(void*)&centers, (void*)&t_part, (void*)&S_part,
                  (void*)&t_glob,  (void*)&S_glob, (void*)&cd_part,
                  (void*)&cd2_part, (void*)&outp,  (void*)&N};
  hipLaunchCooperativeKernel((const void*)fused_density, dim3(NBLK),
                             dim3(THREADS), args, 0, stream);
}

// Round 3
// 25.981 us; speedup vs baseline: 3.7417x; 3.7417x over previous
//
#include <hip/hip_runtime.h>

#define DD 256       // feature dim
#define CC 4096      // number of centers
#define THREADS 256  // 4 waves / block
#define NB 256       // blocks for both kernels
#define RPB (CC / NB)  // 16 rows per block
#define D4 (DD / 4)    // 64 float4 columns per row

// ---------------------------------------------------------------------------
// DensityLoss forward, collapsed O(C^2 D) -> O(C D):
//   t[d]  = sum_i centers[i][d];  S = sum_i ||c_i||^2
//   cd[i] = (C*||c_i||^2 + S - 2*c_i.t) / (C-1)      (diagonal term == 0)
//   out   = (sum cd / C) / var(cd, ddof=1) / N
// Two dispatches. K1: per-block t/S partials (LDS-reduced). K2: per-block
// redundant t finalize + cd rows + last-block (agent-scope ticket) final
// combine. Every reduction is fixed-order -> deterministic, no FP atomics.
// Every ws word is written before it is read on every call.
// ---------------------------------------------------------------------------

__global__ __launch_bounds__(THREADS) void k1_partials(
    const float* __restrict__ centers,
    float* __restrict__ t_part,  // [NB][DD]
    float* __restrict__ S_part,  // [NB]
    int* __restrict__ ticket) {
  const int tx = threadIdx.x, w = tx >> 6, lane = tx & 63, b = blockIdx.x;
  if (b == 0 && tx == 0) *ticket = 0;  // reset K2's ticket every call

  const float4* src =
      (const float4*)centers + (size_t)(b * RPB + w * 4) * D4 + lane;
  float4 v0 = src[0 * D4], v1 = src[1 * D4], v2 = src[2 * D4], v3 = src[3 * D4];

  float4 ta;
  ta.x = (v0.x + v1.x) + (v2.x + v3.x);
  ta.y = (v0.y + v1.y) + (v2.y + v3.y);
  ta.z = (v0.z + v1.z) + (v2.z + v3.z);
  ta.w = (v0.w + v1.w) + (v2.w + v3.w);
  float ss = (v0.x * v0.x + v0.y * v0.y + v0.z * v0.z + v0.w * v0.w) +
             (v1.x * v1.x + v1.y * v1.y + v1.z * v1.z + v1.w * v1.w) +
             (v2.x * v2.x + v2.y * v2.y + v2.z * v2.z + v2.w * v2.w) +
             (v3.x * v3.x + v3.y * v3.y + v3.z * v3.z + v3.w * v3.w);

  __shared__ float4 smT[4][64];
  __shared__ float smS[4];
  smT[w][lane] = ta;
  #pragma unroll
  for (int off = 32; off; off >>= 1) ss += __shfl_xor(ss, off, 64);
  if (lane == 0) smS[w] = ss;
  __syncthreads();
  if (tx < 64) {
    float4 a = smT[0][tx], c = smT[1][tx], d = smT[2][tx], e = smT[3][tx];
    float4 s;
    s.x = (a.x + c.x) + (d.x + e.x);
    s.y = (a.y + c.y) + (d.y + e.y);
    s.z = (a.z + c.z) + (d.z + e.z);
    s.w = (a.w + c.w) + (d.w + e.w);
    ((float4*)t_part)[b * 64 + tx] = s;
  }
  if (tx == 0) S_part[b] = (smS[0] + smS[1]) + (smS[2] + smS[3]);
}

__global__ __launch_bounds__(THREADS) void k2_cd(
    const float* __restrict__ centers, const float* __restrict__ t_part,
    const float* __restrict__ S_part, double* __restrict__ cd_part,
    double* __restrict__ cd2_part, int* __restrict__ ticket,
    float* __restrict__ out, long long N) {
  const int tx = threadIdx.x, w = tx >> 6, lane = tx & 63, b = blockIdx.x;

  __shared__ float smt[DD];
  __shared__ float redS[THREADS];
  __shared__ double smC[4], smC2[4];
  __shared__ int isLast;

  // --- phase A: finalize t (redundant per block; coalesced, L2-resident) ---
  {
    float a0 = 0.f, a1 = 0.f, a2 = 0.f, a3 = 0.f;
    const float* tp = t_part + tx;
    #pragma unroll 16
    for (int p = 0; p < NB; p += 4) {
      a0 += tp[(p + 0) * DD];
      a1 += tp[(p + 1) * DD];
      a2 += tp[(p + 2) * DD];
      a3 += tp[(p + 3) * DD];
    }
    smt[tx] = (a0 + a1) + (a2 + a3);
  }
  redS[tx] = S_part[tx];
  __syncthreads();
  #pragma unroll
  for (int st = 128; st; st >>= 1) {
    if (tx < st) redS[tx] += redS[tx + st];
    __syncthreads();
  }
  const float S = redS[0];
  const float4 t4 = ((const float4*)smt)[lane];

  // --- phase B: cd over this block's 16 rows (4 per wave, unrolled) ---
  const float4* src =
      (const float4*)centers + (size_t)(b * RPB + w * 4) * D4 + lane;
  const float Cf = (float)CC;
  const double inv = 1.0 / (double)(CC - 1);
  double cds = 0.0, cd2 = 0.0;
  #pragma unroll
  for (int r = 0; r < 4; ++r) {
    float4 v = src[r * D4];
    float u = (Cf * v.x - 2.f * t4.x) * v.x + (Cf * v.y - 2.f * t4.y) * v.y +
              (Cf * v.z - 2.f * t4.z) * v.z + (Cf * v.w - 2.f * t4.w) * v.w;
    #pragma unroll
    for (int off = 32; off; off >>= 1) u += __shfl_xor(u, off, 64);
    if (lane == 0) {
      double cd = ((double)u + (double)S) * inv;
      cds += cd;
      cd2 += cd * cd;
    }
  }
  if (lane == 0) { smC[w] = cds; smC2[w] = cd2; }
  __syncthreads();
  if (tx == 0) {
    double bc = (smC[0] + smC[1]) + (smC[2] + smC[3]);
    double bc2 = (smC2[0] + smC2[1]) + (smC2[2] + smC2[3]);
    __hip_atomic_store(&cd_part[b], bc, __ATOMIC_RELEASE,
                       __HIP_MEMORY_SCOPE_AGENT);
    __hip_atomic_store(&cd2_part[b], bc2, __ATOMIC_RELEASE,
                       __HIP_MEMORY_SCOPE_AGENT);
    int old = __hip_atomic_fetch_add(ticket, 1, __ATOMIC_ACQ_REL,
                                     __HIP_MEMORY_SCOPE_AGENT);
    isLast = (old == NB - 1);
  }
  __syncthreads();

  // --- phase C: last block combines NB double partials (fixed-order tree) ---
  if (isLast) {
    __shared__ double rc[THREADS], rc2[THREADS];
    rc[tx] = __hip_atomic_load(&cd_part[tx], __ATOMIC_RELAXED,
                               __HIP_MEMORY_SCOPE_AGENT);
    rc2[tx] = __hip_atomic_load(&cd2_part[tx], __ATOMIC_RELAXED,
                                __HIP_MEMORY_SCOPE_AGENT);
    __syncthreads();
    #pragma unroll
    for (int st = 128; st; st >>= 1) {
      if (tx < st) { rc[tx] += rc[tx + st]; rc2[tx] += rc2[tx + st]; }
      __syncthreads();
    }
    if (tx == 0) {
      double s = rc[0], s2 = rc2[0];
      double mean = s / (double)CC;
      double var = (s2 - s * s / (double)CC) / (double)(CC - 1);
      out[0] = (float)(mean / var / (double)N);
    }
  }
}

extern "C" void kernel_launch(void* const* d_in, const int* in_sizes, int n_in,
                              void* d_out, int out_size, void* d_ws,
                              size_t ws_size, hipStream_t stream) {
  const float* centers = (const float*)d_in[0];
  long long N = (long long)in_sizes[2];  // labels.shape[0]
  (void)n_in; (void)out_size; (void)ws_size;

  // ws layout (16B aligned): t_part 256 KB | S_part 1 KB | cd 2 KB | cd2 2 KB
  // | ticket
  char* ws = (char*)d_ws;
  float* t_part = (float*)ws;                          // NB*DD floats
  float* S_part = (float*)(ws + (size_t)NB * DD * 4);  // NB floats
  double* cd_part = (double*)(ws + (size_t)NB * DD * 4 + NB * 4);
  double* cd2_part = cd_part + NB;
  int* ticket = (int*)(cd2_part + NB);
  float* outp = (float*)d_out;

  hipLaunchKernelGGL(k1_partials, dim3(NB), dim3(THREADS), 0, stream, centers,
                     t_part, S_part, ticket);
  hipLaunchKernelGGL(k2_cd, dim3(NB), dim3(THREADS), 0, stream, centers,
                     t_part, S_part, cd_part, cd2_part, ticket, outp,
                     (long long)N);
}

// Round 4
// 22.473 us; speedup vs baseline: 4.3257x; 1.1561x over previous
//
#include <hip/hip_runtime.h>

#define DD 256        // feature dim
#define CC 4096       // number of centers
#define NB 64         // blocks (one barrier group)
#define TPB 1024      // threads/block = 16 waves
#define RPB (CC / NB) // 64 rows per block (4 per wave)
#define D4 (DD / 4)   // 64 float4 columns per row

// ---------------------------------------------------------------------------
// DensityLoss forward, collapsed O(C^2 D) -> O(C D), ONE kernel node:
//   t[d]  = sum_i centers[i][d];  S = sum_i ||c_i||^2
//   cd[i] = (C*||c_i||^2 + S - 2*c_i.t) / (C-1)      (diagonal term == 0)
//   out   = (sum cd / C) / var(cd, ddof=1) / N
// Grid exchange via hand-rolled agent-scope arrival barrier (counters zeroed
// by a memset node each call -> immune to the 0xAA ws poison). Rows live in
// registers across the barrier; centers is read exactly once. Every
// reduction is a fixed-order tree/butterfly -> deterministic; the
// nondeterministic "last block" identity only picks WHO runs the final
// fixed-order combine, not its value.
// ---------------------------------------------------------------------------
__global__ __launch_bounds__(TPB) void fused_density(
    const float* __restrict__ centers,
    float* __restrict__ t_part,    // [NB][DD]
    float* __restrict__ S_part,    // [NB]
    double* __restrict__ cd_part,  // [NB]
    double* __restrict__ cd2_part, // [NB]
    int* __restrict__ counters,    // [2], zeroed by memset node
    float* __restrict__ out, long long N) {
  const int tx = threadIdx.x, w = tx >> 6, lane = tx & 63, b = blockIdx.x;

  __shared__ float4 smT[16][64];   // wave column partials (16 KB)
  __shared__ float smt[DD];        // final t
  __shared__ float sS[64];
  __shared__ double rc[64], rc2[64];
  __shared__ double sC[16], sC2[16];
  __shared__ int lastFlag;

  // ---- phase 1: per-block column sums + sum-of-squares (rows -> regs) ----
  const float4* src =
      (const float4*)centers + (size_t)(b * RPB + w * 4) * D4 + lane;
  float4 v0 = src[0 * D4], v1 = src[1 * D4], v2 = src[2 * D4], v3 = src[3 * D4];

  float4 ta;
  ta.x = (v0.x + v1.x) + (v2.x + v3.x);
  ta.y = (v0.y + v1.y) + (v2.y + v3.y);
  ta.z = (v0.z + v1.z) + (v2.z + v3.z);
  ta.w = (v0.w + v1.w) + (v2.w + v3.w);
  smT[w][lane] = ta;
  float ss = (v0.x * v0.x + v0.y * v0.y + v0.z * v0.z + v0.w * v0.w) +
             (v1.x * v1.x + v1.y * v1.y + v1.z * v1.z + v1.w * v1.w) +
             (v2.x * v2.x + v2.y * v2.y + v2.z * v2.z + v2.w * v2.w) +
             (v3.x * v3.x + v3.y * v3.y + v3.z * v3.z + v3.w * v3.w);
  #pragma unroll
  for (int off = 32; off; off >>= 1) ss += __shfl_xor(ss, off, 64);
  if (lane == 0) sS[w] = ss;
  __syncthreads();
  if (tx < 64) {
    float4 s = smT[0][tx];
    #pragma unroll
    for (int k = 1; k < 16; ++k) {
      float4 o = smT[k][tx];
      s.x += o.x; s.y += o.y; s.z += o.z; s.w += o.w;
    }
    ((float4*)t_part)[b * 64 + tx] = s;
  }
  if (tx == 0) {
    float s = 0.f;
    #pragma unroll
    for (int k = 0; k < 16; ++k) s += sS[k];
    S_part[b] = s;
  }
  __syncthreads();  // block's t_part/S_part stores ordered before tx0 release

  // ---- grid arrival barrier (agent scope; proven pattern from R3) ----
  if (tx == 0) {
    __hip_atomic_fetch_add(&counters[0], 1, __ATOMIC_ACQ_REL,
                           __HIP_MEMORY_SCOPE_AGENT);
    while (__hip_atomic_load(&counters[0], __ATOMIC_ACQUIRE,
                             __HIP_MEMORY_SCOPE_AGENT) < NB)
      __builtin_amdgcn_s_sleep(1);
  }
  __syncthreads();  // leader's acquire + block barrier publishes to all waves

  // ---- phase 2: redundant t finalize (64 unrolled coalesced loads) + S ----
  if (tx < DD) {
    float a0 = 0.f, a1 = 0.f, a2 = 0.f, a3 = 0.f;
    const float* tp = t_part + tx;
    #pragma unroll
    for (int p = 0; p < NB; p += 4) {
      a0 += tp[(p + 0) * DD];
      a1 += tp[(p + 1) * DD];
      a2 += tp[(p + 2) * DD];
      a3 += tp[(p + 3) * DD];
    }
    smt[tx] = (a0 + a1) + (a2 + a3);
  } else if (tx >= 256 && tx < 320) {
    sS[tx - 256] = S_part[tx - 256];
  }
  __syncthreads();
  if (tx < 32) sS[tx] += sS[tx + 32];
  __syncthreads();
  if (tx < 16) sS[tx] += sS[tx + 16];
  __syncthreads();
  if (tx < 8) sS[tx] += sS[tx + 8];
  __syncthreads();
  if (tx < 4) sS[tx] += sS[tx + 4];
  __syncthreads();
  if (tx < 2) sS[tx] += sS[tx + 2];
  __syncthreads();
  if (tx == 0) sS[0] += sS[1];
  __syncthreads();
  const float S = sS[0];
  const float4 t4 = ((const float4*)smt)[lane];

  // ---- phase 3: cd for this block's rows (still in registers) ----
  const float Cf = (float)CC;
  const double inv = 1.0 / (double)(CC - 1);
  double cds = 0.0, cd2 = 0.0;
  #pragma unroll
  for (int r = 0; r < 4; ++r) {
    float4 v = (r == 0) ? v0 : (r == 1) ? v1 : (r == 2) ? v2 : v3;
    float u = (Cf * v.x - 2.f * t4.x) * v.x + (Cf * v.y - 2.f * t4.y) * v.y +
              (Cf * v.z - 2.f * t4.z) * v.z + (Cf * v.w - 2.f * t4.w) * v.w;
    #pragma unroll
    for (int off = 32; off; off >>= 1) u += __shfl_xor(u, off, 64);
    if (lane == 0) {
      double cd = ((double)u + (double)S) * inv;
      cds += cd;
      cd2 += cd * cd;
    }
  }
  if (lane == 0) { sC[w] = cds; sC2[w] = cd2; }
  __syncthreads();
  if (tx == 0) {
    double bc = 0.0, bc2 = 0.0;
    #pragma unroll
    for (int k = 0; k < 16; ++k) { bc += sC[k]; bc2 += sC2[k]; }
    __hip_atomic_store(&cd_part[b], bc, __ATOMIC_RELEASE,
                       __HIP_MEMORY_SCOPE_AGENT);
    __hip_atomic_store(&cd2_part[b], bc2, __ATOMIC_RELEASE,
                       __HIP_MEMORY_SCOPE_AGENT);
    int old = __hip_atomic_fetch_add(&counters[1], 1, __ATOMIC_ACQ_REL,
                                     __HIP_MEMORY_SCOPE_AGENT);
    lastFlag = (old == NB - 1);
  }
  __syncthreads();

  // ---- phase 4: last-arriving block does the fixed-order final combine ----
  if (lastFlag) {
    if (tx < 64) {
      rc[tx] = __hip_atomic_load(&cd_part[tx], __ATOMIC_RELAXED,
                                 __HIP_MEMORY_SCOPE_AGENT);
      rc2[tx] = __hip_atomic_load(&cd2_part[tx], __ATOMIC_RELAXED,
                                  __HIP_MEMORY_SCOPE_AGENT);
    }
    __syncthreads();
    #pragma unroll
    for (int st = 32; st; st >>= 1) {
      if (tx < st) { rc[tx] += rc[tx + st]; rc2[tx] += rc2[tx + st]; }
      __syncthreads();
    }
    if (tx == 0) {
      double s = rc[0], s2 = rc2[0];
      double mean = s / (double)CC;
      double var = (s2 - s * s / (double)CC) / (double)(CC - 1);
      out[0] = (float)(mean / var / (double)N);
    }
  }
}

extern "C" void kernel_launch(void* const* d_in, const int* in_sizes, int n_in,
                              void* d_out, int out_size, void* d_ws,
                              size_t ws_size, hipStream_t stream) {
  const float* centers = (const float*)d_in[0];
  long long N = (long long)in_sizes[2];  // labels.shape[0]
  (void)n_in; (void)out_size; (void)ws_size;

  // ws layout (8B aligned): t_part 64KB | cd 512B | cd2 512B | S 256B | cnt 8B
  char* ws = (char*)d_ws;
  float* t_part = (float*)ws;
  double* cd_part = (double*)(ws + 65536);
  double* cd2_part = (double*)(ws + 65536 + 512);
  float* S_part = (float*)(ws + 65536 + 1024);
  int* counters = (int*)(ws + 65536 + 1024 + 256);
  float* outp = (float*)d_out;

  hipMemsetAsync(counters, 0, 2 * sizeof(int), stream);
  hipLaunchKernelGGL(fused_density, dim3(NB), dim3(TPB), 0, stream, centers,
                     t_part, S_part, cd_part, cd2_part, counters, outp, N);
}

// Round 5
// 16.863 us; speedup vs baseline: 5.7648x; 1.3327x over previous
//
#include <hip/hip_runtime.h>

#define DD 256        // feature dim
#define CC 4096       // number of centers
#define NB 64         // blocks (one barrier group)
#define TPB 1024      // threads/block = 16 waves
#define RPB (CC / NB) // 64 rows per block (4 per wave)
#define D4 (DD / 4)   // 64 float4 columns per row
#define MAGIC 0x05F3A9C1  // != 0x00000000 (self-reset) and != 0xAAAAAAAA (poison)

// ---------------------------------------------------------------------------
// DensityLoss forward, collapsed O(C^2 D) -> O(C D), ONE graph node:
//   t[d]  = sum_i centers[i][d];  S = sum_i ||c_i||^2
//   cd[i] = (C*||c_i||^2 + S - 2*c_i.t) / (C-1)      (diagonal term == 0)
//   out   = (sum cd / C) / var(cd, ddof=1) / N
// Grid exchange via magic-value flags: block b release-stores flag[b]=MAGIC
// after publishing its partials; consumers acquire-spin per flag. Block 0
// resets all flags to 0 at the very end (after every block's flag2 is set,
// so nobody is still reading them) -> next call needs no memset node, and
// the one-time 0xAA ws poison is also != MAGIC. All reductions fixed-order
// (register/LDS trees + wave butterflies) -> deterministic output; block 0
// always runs the final combine.
// ---------------------------------------------------------------------------
__global__ __launch_bounds__(TPB) void fused_density(
    const float* __restrict__ centers,
    float* __restrict__ t_part,    // [NB][DD]
    float* __restrict__ S_part,    // [NB]
    double* __restrict__ cd_part,  // [NB]
    double* __restrict__ cd2_part, // [NB]
    int* __restrict__ flag1,       // [NB]
    int* __restrict__ flag2,       // [NB]
    float* __restrict__ out, long long N) {
  const int tx = threadIdx.x, w = tx >> 6, lane = tx & 63, b = blockIdx.x;

  __shared__ float4 smT[16][64];  // wave column partials (16 KB)
  __shared__ float sm2[2][DD];    // half-reduced t partials
  __shared__ float smt[DD];       // final t
  __shared__ float sSfin;
  __shared__ float sS[16];
  __shared__ double sC[16], sC2[16];
  __shared__ double rc[64], rc2[64];

  // ---- phase 1: per-block column sums + sum-of-squares (rows -> regs) ----
  const float4* src =
      (const float4*)centers + (size_t)(b * RPB + w * 4) * D4 + lane;
  float4 v0 = src[0 * D4], v1 = src[1 * D4], v2 = src[2 * D4], v3 = src[3 * D4];

  float4 ta;
  ta.x = (v0.x + v1.x) + (v2.x + v3.x);
  ta.y = (v0.y + v1.y) + (v2.y + v3.y);
  ta.z = (v0.z + v1.z) + (v2.z + v3.z);
  ta.w = (v0.w + v1.w) + (v2.w + v3.w);
  smT[w][lane] = ta;
  float ss = (v0.x * v0.x + v0.y * v0.y + v0.z * v0.z + v0.w * v0.w) +
             (v1.x * v1.x + v1.y * v1.y + v1.z * v1.z + v1.w * v1.w) +
             (v2.x * v2.x + v2.y * v2.y + v2.z * v2.z + v2.w * v2.w) +
             (v3.x * v3.x + v3.y * v3.y + v3.z * v3.z + v3.w * v3.w);
  #pragma unroll
  for (int off = 32; off; off >>= 1) ss += __shfl_xor(ss, off, 64);
  if (lane == 0) sS[w] = ss;
  __syncthreads();
  if (tx < 64) {
    float4 s = smT[0][tx];
    #pragma unroll
    for (int k = 1; k < 16; ++k) {
      float4 o = smT[k][tx];
      s.x += o.x; s.y += o.y; s.z += o.z; s.w += o.w;
    }
    ((float4*)t_part)[b * 64 + tx] = s;
  }
  if (tx == 0) {
    float s = 0.f;
    #pragma unroll
    for (int k = 0; k < 16; ++k) s += sS[k];
    S_part[b] = s;
  }
  __syncthreads();  // block's t_part/S_part stores complete before release
  if (tx == 0)
    __hip_atomic_store(&flag1[b], MAGIC, __ATOMIC_RELEASE,
                       __HIP_MEMORY_SCOPE_AGENT);

  // ---- grid barrier: every block waits for all 64 flag1 (parallel spin) ---
  if (tx < NB) {
    while (__hip_atomic_load(&flag1[tx], __ATOMIC_ACQUIRE,
                             __HIP_MEMORY_SCOPE_AGENT) != MAGIC)
      __builtin_amdgcn_s_sleep(1);
  }
  __syncthreads();

  // ---- phase 2: redundant t finalize (512 thr, 8-way ILP) + S butterfly ---
  if (tx < 512) {
    const int col = tx & 255, half = tx >> 8;
    const float* tp = t_part + (size_t)half * 32 * DD + col;
    float a0 = 0.f, a1 = 0.f, a2 = 0.f, a3 = 0.f;
    float a4 = 0.f, a5 = 0.f, a6 = 0.f, a7 = 0.f;
    #pragma unroll
    for (int p = 0; p < 32; p += 8) {
      a0 += tp[(p + 0) * DD]; a1 += tp[(p + 1) * DD];
      a2 += tp[(p + 2) * DD]; a3 += tp[(p + 3) * DD];
      a4 += tp[(p + 4) * DD]; a5 += tp[(p + 5) * DD];
      a6 += tp[(p + 6) * DD]; a7 += tp[(p + 7) * DD];
    }
    sm2[half][col] = ((a0 + a1) + (a2 + a3)) + ((a4 + a5) + (a6 + a7));
  } else if (tx >= 512 && tx < 576) {  // wave 8: S via one 64-lane butterfly
    float sv = S_part[tx - 512];
    #pragma unroll
    for (int off = 32; off; off >>= 1) sv += __shfl_xor(sv, off, 64);
    if (tx == 512) sSfin = sv;
  }
  __syncthreads();
  if (tx < DD) smt[tx] = sm2[0][tx] + sm2[1][tx];
  __syncthreads();
  const float S = sSfin;
  const float4 t4 = ((const float4*)smt)[lane];

  // ---- phase 3: cd for this block's rows (still in registers) ----
  const float Cf = (float)CC;
  const double inv = 1.0 / (double)(CC - 1);
  double cds = 0.0, cd2 = 0.0;
  #pragma unroll
  for (int r = 0; r < 4; ++r) {
    float4 v = (r == 0) ? v0 : (r == 1) ? v1 : (r == 2) ? v2 : v3;
    float u = (Cf * v.x - 2.f * t4.x) * v.x + (Cf * v.y - 2.f * t4.y) * v.y +
              (Cf * v.z - 2.f * t4.z) * v.z + (Cf * v.w - 2.f * t4.w) * v.w;
    #pragma unroll
    for (int off = 32; off; off >>= 1) u += __shfl_xor(u, off, 64);
    if (lane == 0) {
      double cd = ((double)u + (double)S) * inv;
      cds += cd;
      cd2 += cd * cd;
    }
  }
  if (lane == 0) { sC[w] = cds; sC2[w] = cd2; }
  __syncthreads();
  if (tx == 0) {
    double bc = 0.0, bc2 = 0.0;
    #pragma unroll
    for (int k = 0; k < 16; ++k) { bc += sC[k]; bc2 += sC2[k]; }
    __hip_atomic_store(&cd_part[b], bc, __ATOMIC_RELEASE,
                       __HIP_MEMORY_SCOPE_AGENT);
    __hip_atomic_store(&cd2_part[b], bc2, __ATOMIC_RELEASE,
                       __HIP_MEMORY_SCOPE_AGENT);
    __hip_atomic_store(&flag2[b], MAGIC, __ATOMIC_RELEASE,
                       __HIP_MEMORY_SCOPE_AGENT);
  }

  // ---- phase 4: block 0 combines all partials, then resets the flags ----
  if (b == 0) {
    if (tx < NB) {
      while (__hip_atomic_load(&flag2[tx], __ATOMIC_ACQUIRE,
                               __HIP_MEMORY_SCOPE_AGENT) != MAGIC)
        __builtin_amdgcn_s_sleep(1);
      rc[tx] = cd_part[tx];
      rc2[tx] = cd2_part[tx];
    }
    __syncthreads();
    #pragma unroll
    for (int st = 32; st; st >>= 1) {
      if (tx < st) { rc[tx] += rc[tx + st]; rc2[tx] += rc2[tx + st]; }
      __syncthreads();
    }
    if (tx == 0) {
      double s = rc[0], s2 = rc2[0];
      double mean = s / (double)CC;
      double var = (s2 - s * s / (double)CC) / (double)(CC - 1);
      out[0] = (float)(mean / var / (double)N);
    }
    // all blocks have passed both flag phases (flag2 all MAGIC) -> safe reset
    if (tx < NB) {
      __hip_atomic_store(&flag1[tx], 0, __ATOMIC_RELEASE,
                         __HIP_MEMORY_SCOPE_AGENT);
      __hip_atomic_store(&flag2[tx], 0, __ATOMIC_RELEASE,
                         __HIP_MEMORY_SCOPE_AGENT);
    }
  }
}

extern "C" void kernel_launch(void* const* d_in, const int* in_sizes, int n_in,
                              void* d_out, int out_size, void* d_ws,
                              size_t ws_size, hipStream_t stream) {
  const float* centers = (const float*)d_in[0];
  long long N = (long long)in_sizes[2];  // labels.shape[0]
  (void)n_in; (void)out_size; (void)ws_size;

  // ws layout: t_part 64KB | S_part 256B | pad | cd 512B | cd2 512B | flags
  char* ws = (char*)d_ws;
  float* t_part = (float*)ws;                    // 65536 B
  float* S_part = (float*)(ws + 65536);          // 256 B
  double* cd_part = (double*)(ws + 66048);       // 512 B (8B aligned)
  double* cd2_part = (double*)(ws + 66560);      // 512 B
  int* flag1 = (int*)(ws + 67072);               // 256 B
  int* flag2 = (int*)(ws + 67328);               // 256 B
  float* outp = (float*)d_out;

  hipLaunchKernelGGL(fused_density, dim3(NB), dim3(TPB), 0, stream, centers,
                     t_part, S_part, cd_part, cd2_part, flag1, flag2, outp, N);
}